// Round 8
// baseline (567.258 us; speedup 1.0000x reference)
//
#include <hip/hip_runtime.h>
#include <hip/hip_bf16.h>
#include <math.h>

#define NUM_EMB 8192
#define EMB_DIM 256
#define NTOK    16384      // 16 * 32 * 32
#define HW      1024
#define QELEMS  4194304    // 16 * 256 * 1024
#define DECAY   0.99f
#define OMD     0.01f
#define COMMIT  0.25f
#define EPS_    1e-5f
#define MARGIN  0.6f
#define NSLICE  16         // codes per slice = 512

typedef _Float16 h8 __attribute__((ext_vector_type(8)));
typedef float    f4 __attribute__((ext_vector_type(4)));

#define GLD16(gptr, lptr) \
  __builtin_amdgcn_global_load_lds((const __attribute__((address_space(1))) void*)(gptr), \
                                   (__attribute__((address_space(3))) void*)(lptr), 16, 0, 0)

// ---------------- k_prep: x->Ap(f16)+xT(f32), emb->Bp(f16 stream order), esq --------
// Ap fragment layout: [(mt*8+kc)*64+lane]*8 halves; token = mt*16+(lane&15),
// d = kc*32 + (lane>>4)*8 + j.
// Bp STREAM layout: [bS][wn][nt*8+kc][j][lane]*8 halves so each k_dist wave reads
// its 128KB B-slice strictly sequentially (pointer += 2KB per iter, imm offsets).
__global__ __launch_bounds__(256)
void k_prep(const float* __restrict__ x, const float* __restrict__ emb,
            _Float16* __restrict__ Ap, _Float16* __restrict__ Bp,
            float* __restrict__ xT, float* __restrict__ esq,
            float* __restrict__ counts) {
    int bb = blockIdx.x;
    if (bb < 2048) {
        int g = bb * 256 + threadIdx.x;
        int lane = g & 63;
        int kc = (g >> 6) & 7;
        int mt = g >> 9;                         // 0..1023
        int tok = mt * 16 + (lane & 15);
        int b = tok >> 10, hw = tok & 1023;
        int d0 = kc * 32 + (lane >> 4) * 8;
        const float* src = x + (size_t)b * 262144 + (size_t)d0 * 1024 + hw;
        h8 hi; float tmp[8];
        #pragma unroll
        for (int u = 0; u < 8; u++) {
            float v = src[(size_t)u * 1024];
            hi[u] = (_Float16)v;
            tmp[u] = v;
        }
        *(h8*)(Ap + ((size_t)(mt * 8 + kc) * 64 + lane) * 8) = hi;
        *(float4*)(xT + (size_t)tok * 256 + d0)     = *(float4*)(&tmp[0]);
        *(float4*)(xT + (size_t)tok * 256 + d0 + 4) = *(float4*)(&tmp[4]);
    } else if (bb < 3072) {
        int g = (bb - 2048) * 256 + threadIdx.x;
        int lane = g & 63;
        int kc = (g >> 6) & 7;
        int nf = g >> 9;                         // 0..511 (16-code group)
        int n = nf * 16 + (lane & 15);
        int d0 = kc * 32 + (lane >> 4) * 8;
        const float* src = emb + (size_t)n * EMB_DIM + d0;
        h8 hi;
        #pragma unroll
        for (int u = 0; u < 8; u++) hi[u] = (_Float16)src[u];
        // nf = bS*32 + nt*8 + wn*4 + j
        int bS = nf >> 5, nt = (nf >> 3) & 3, wn = (nf >> 2) & 1, j = nf & 3;
        size_t addr = ((((size_t)(bS * 2 + wn) * 32 + nt * 8 + kc) * 4 + j) * 64 + lane) * 8;
        *(h8*)(Bp + addr) = hi;
    } else if (bb < 5120) {
        int k = (bb - 3072) * 4 + (threadIdx.x >> 6);
        int lane = threadIdx.x & 63;
        const float* row = emb + (size_t)k * EMB_DIM;
        float4 v = *(const float4*)(row + lane * 4);
        float s = v.x * v.x + v.y * v.y + v.z * v.z + v.w * v.w;
        #pragma unroll
        for (int m = 32; m >= 1; m >>= 1) s += __shfl_xor(s, m);
        if (lane == 0) esq[k] = s;
    } else {
        counts[(bb - 5120) * 256 + threadIdx.x] = 0.0f;
    }
}

// ---------------- k_dist: 64x512 block, streamed B, packed top-2 --------------------
// Biased distance dv = (esq+4096) - 2*dot in (4096,8192) -> fixed exponent; low 4
// mantissa bits carry (nt<<2)|j. Integer min/max keeps top-2 per lane.
__global__ __launch_bounds__(256, 5)
void k_dist(const _Float16* __restrict__ Ap, const _Float16* __restrict__ Bp,
            const float* __restrict__ esq, float4* __restrict__ pairs) {
    __shared__ _Float16 Abuf[64 * 256];     // 32 KB (merge buffer overlaid after loop)

    const int tid    = threadIdx.x;
    const int lane   = tid & 63;
    const int lane16 = lane & 15;
    const int w      = tid >> 6;
    const int wm     = w >> 1, wn = w & 1;
    const int bS     = blockIdx.x >> 8;     // 0..15 (slice-major: L2 reuse of Bp)
    const int bM     = blockIdx.x & 255;    // 0..255
    const int m0     = bM * 64;

    // stage A tile once: 32 KB contiguous from Ap
    #pragma unroll
    for (int s = 0; s < 8; s++) {
        int idx = s * 256 + tid;
        GLD16(Ap + (size_t)bM * 16384 + (size_t)idx * 8, Abuf + idx * 8);
    }

    // preload biased esq for all (nt, j) this lane will see
    float ev[16];
    #pragma unroll
    for (int nt = 0; nt < 4; nt++)
        #pragma unroll
        for (int j = 0; j < 4; j++)
            ev[nt * 4 + j] = esq[bS * 512 + nt * 128 + wn * 64 + j * 16 + lane16] + 4096.0f;

    int b1[8], s1[8];
    #pragma unroll
    for (int r = 0; r < 8; r++) { b1[r] = 0x7f7fffff; s1[r] = 0x7f7fffff; }

    __syncthreads();   // staging barrier

    // wave's sequential B stream: 32 segs x 4 frags x 512 halfwords = 128 KB
    const _Float16* Bw = Bp + (size_t)(bS * 2 + wn) * 65536 + (size_t)lane * 8;

    f4 acc[2][4] = {};
    h8 bFn[4];
    #pragma unroll
    for (int j = 0; j < 4; j++) bFn[j] = *(const h8*)(Bw + j * 512);
    const _Float16* Bnext = Bw + 2048;

    #pragma unroll 8
    for (int t = 0; t < 32; t++) {
        const int nt = t >> 3, kc = t & 7;
        h8 bF[4];
        #pragma unroll
        for (int j = 0; j < 4; j++) bF[j] = bFn[j];
        if (t < 31) {
            #pragma unroll
            for (int j = 0; j < 4; j++)
                bFn[j] = *(const h8*)(Bnext + j * 512);
            Bnext += 2048;
        }
        h8 aF[2];
        #pragma unroll
        for (int i = 0; i < 2; i++)
            aF[i] = *(const h8*)(Abuf + (((wm * 2 + i) * 8 + kc) * 64 + lane) * 8);
        #pragma unroll
        for (int i = 0; i < 2; i++)
            #pragma unroll
            for (int j = 0; j < 4; j++)
                acc[i][j] = __builtin_amdgcn_mfma_f32_16x16x32_f16(aF[i], bF[j], acc[i][j], 0, 0, 0);

        if (kc == 7) {   // per-nt epilogue: packed top-2 update, then reset acc
            #pragma unroll
            for (int i = 0; i < 2; i++)
                #pragma unroll
                for (int reg = 0; reg < 4; reg++) {
                    const int r = i * 4 + reg;
                    #pragma unroll
                    for (int j = 0; j < 4; j++) {
                        float dv = fmaf(-2.0f, acc[i][j][reg], ev[nt * 4 + j]);
                        int iv = (__float_as_int(dv) & ~0xF) | (nt << 2) | j;
                        int mx = max(b1[r], iv);
                        b1[r] = min(b1[r], iv);
                        s1[r] = min(s1[r], mx);
                    }
                }
            #pragma unroll
            for (int i = 0; i < 2; i++)
                #pragma unroll
                for (int j = 0; j < 4; j++)
                    acc[i][j] = (f4){0.0f, 0.0f, 0.0f, 0.0f};
        }
    }

    __syncthreads();   // Abuf globally dead -> safe to overlay merge buffer
    float4* sv2 = (float4*)Abuf;

    // unpack (nt,j) codes -> full indices, then cross-lane16 exact top-2 merge
    #pragma unroll
    for (int i = 0; i < 2; i++) {
        #pragma unroll
        for (int reg = 0; reg < 4; reg++) {
            const int rr = i * 4 + reg;
            int bv = b1[rr], sv = s1[rr];
            int bki = bS * 512 + ((bv >> 2) & 3) * 128 + (bv & 3) * 16 + wn * 64 + lane16;
            int ski = bS * 512 + ((sv >> 2) & 3) * 128 + (sv & 3) * 16 + wn * 64 + lane16;
            #pragma unroll
            for (int mask = 1; mask <= 8; mask <<= 1) {
                int ov  = __shfl_xor(bv, mask);  int oki  = __shfl_xor(bki, mask);
                int ov2 = __shfl_xor(sv, mask);  int oki2 = __shfl_xor(ski, mask);
                if (ov < bv || (ov == bv && oki < bki)) {
                    int ns = bv; int nsi = bki;
                    if (ov2 < ns) { ns = ov2; nsi = oki2; }
                    bv = ov; bki = oki; sv = ns; ski = nsi;
                } else if (ov < sv) { sv = ov; ski = oki; }
            }
            if (lane16 == 0) {
                int r = (wm * 2 + i) * 16 + ((lane >> 4) << 2) + reg;
                sv2[wn * 64 + r] = make_float4(__int_as_float(bv), __int_as_float(bki),
                                               __int_as_float(sv), __int_as_float(ski));
            }
        }
    }
    __syncthreads();
    if (tid < 64) {
        float4 A = sv2[tid], C = sv2[64 + tid];
        float a1 = A.x, a2 = A.z, c1 = C.x, c2 = C.z;
        int a1i = __float_as_int(A.y), a2i = __float_as_int(A.w);
        int c1i = __float_as_int(C.y), c2i = __float_as_int(C.w);
        float b, s; int bi, si;
        if (c1 < a1 || (c1 == a1 && c1i < a1i)) {
            b = c1; bi = c1i; s = a1; si = a1i;
            if (c2 < s) { s = c2; si = c2i; }
        } else {
            b = a1; bi = a1i; s = a2; si = a2i;
            if (c1 < s) { s = c1; si = c1i; }
        }
        pairs[(size_t)(m0 + tid) * NSLICE + bS] = make_float4(b, __int_as_float(bi), s, __int_as_float(si));
    }
}

// ---------------- k_rq: fused refine (exact fp32 argmin) + coalesced q_st + loss ----
__global__ __launch_bounds__(512)
void k_rq(const float4* __restrict__ pairs, const float* __restrict__ xT,
          const float* __restrict__ emb, const float* __restrict__ esq,
          const float* __restrict__ x,
          int* __restrict__ idx_i32, float* __restrict__ out_idxf,
          float* __restrict__ counts, float* __restrict__ out_qst,
          float* __restrict__ loss_parts) {
    __shared__ float Q[64 * 257];   // winner rows, stride 257
    __shared__ float wsum[8];
    int tid = threadIdx.x;
    int lane = tid & 63, wid = tid >> 6;
    int tok0 = blockIdx.x * 64;
    int b = tok0 >> 10, hw0 = tok0 & 1023;

    for (int s = 0; s < 8; s++) {
        int tl = wid * 8 + s;
        int tok = tok0 + tl;
        float4 p = (lane < NSLICE) ? pairs[(size_t)tok * NSLICE + lane]
                                   : make_float4(3.4e38f, __int_as_float(0x7fffffff),
                                                 3.4e38f, __int_as_float(0x7fffffff));
        float v1 = p.x, v2 = p.z;
        int i1 = __float_as_int(p.y), i2 = __float_as_int(p.w);

        float bv = v1; int bi = i1;
        #pragma unroll
        for (int mask = 1; mask <= 32; mask <<= 1) {
            float ov = __shfl_xor(bv, mask); int oi = __shfl_xor(bi, mask);
            if (ov < bv || (ov == bv && oi < bi)) { bv = ov; bi = oi; }
        }
        float thresh = bv + MARGIN;
        float4 xv = *(const float4*)(xT + (size_t)tok * 256 + lane * 4);

        unsigned long long m1 = __ballot(v1 <= thresh);
        unsigned long long m2 = __ballot(v2 <= thresh);
        float bestd = 3.4e38f; int besti = 0x7fffffff;
        while (m1 | m2) {
            int k;
            if (m1) { int l = __ffsll(m1) - 1; m1 &= m1 - 1; k = __shfl(i1, l); }
            else    { int l = __ffsll(m2) - 1; m2 &= m2 - 1; k = __shfl(i2, l); }
            float4 e4 = *(const float4*)(emb + (size_t)k * EMB_DIM + lane * 4);
            float d = xv.x * e4.x + xv.y * e4.y + xv.z * e4.z + xv.w * e4.w;
            #pragma unroll
            for (int mask = 1; mask <= 32; mask <<= 1) d += __shfl_xor(d, mask);
            float dist = esq[k] - 2.0f * d;
            if (dist < bestd || (dist == bestd && k < besti)) { bestd = dist; besti = k; }
        }
        float4 e4 = *(const float4*)(emb + (size_t)besti * EMB_DIM + lane * 4);
        float* q = Q + tl * 257 + lane * 4;
        q[0] = e4.x; q[1] = e4.y; q[2] = e4.z; q[3] = e4.w;
        if (lane == 0) {
            idx_i32[tok] = besti;
            out_idxf[tok] = (float)besti;
            atomicAdd(&counts[besti], 1.0f);
        }
    }
    __syncthreads();

    // phase 2: coalesced NCHW straight-through write + loss
    int lane16 = tid & 15, dg = tid >> 4;      // dg 0..31
    int hwoff = lane16 * 4;
    float sq = 0.0f;
    #pragma unroll 2
    for (int it = 0; it < 8; it++) {
        int d = it * 32 + dg;
        const float* xb = x + (size_t)b * 262144 + (size_t)d * 1024 + hw0 + hwoff;
        float4 xv = *(const float4*)xb;
        float q0 = Q[(hwoff + 0) * 257 + d];
        float q1 = Q[(hwoff + 1) * 257 + d];
        float q2 = Q[(hwoff + 2) * 257 + d];
        float q3 = Q[(hwoff + 3) * 257 + d];
        float d0 = q0 - xv.x, d1 = q1 - xv.y, d2 = q2 - xv.z, d3 = q3 - xv.w;
        float4 o; o.x = xv.x + d0; o.y = xv.y + d1; o.z = xv.z + d2; o.w = xv.w + d3;
        *(float4*)(out_qst + (size_t)b * 262144 + (size_t)d * 1024 + hw0 + hwoff) = o;
        sq += d0 * d0 + d1 * d1 + d2 * d2 + d3 * d3;
    }
    #pragma unroll
    for (int m = 32; m >= 1; m >>= 1) sq += __shfl_xor(sq, m);
    if (lane == 0) wsum[wid] = sq;
    __syncthreads();
    if (tid == 0) {
        float t = 0.0f;
        #pragma unroll
        for (int u = 0; u < 8; u++) t += wsum[u];
        loss_parts[blockIdx.x] = t;
    }
}

// ---------------- k_ivt_stats: 1024-thread prefix sum + scatter + stats -------------
__global__ __launch_bounds__(1024)
void k_ivt_stats(const float* __restrict__ counts, const int* __restrict__ idx_i32,
                 const float* __restrict__ cs, const float* __restrict__ loss_parts,
                 int* __restrict__ offsets, int* __restrict__ toklist,
                 float* __restrict__ n_out, float* __restrict__ out) {
    __shared__ int part[1024];
    __shared__ int cur[NUM_EMB];
    int t = threadIdx.x;
    int base = t * 8;
    int loc[8]; int s = 0;
    #pragma unroll
    for (int u = 0; u < 8; u++) { loc[u] = s; s += (int)counts[base + u]; }
    part[t] = s;
    __syncthreads();
    for (int off = 1; off < 1024; off <<= 1) {
        int add = (t >= off) ? part[t - off] : 0;
        __syncthreads();
        part[t] += add;
        __syncthreads();
    }
    int excl = part[t] - s;
    #pragma unroll
    for (int u = 0; u < 8; u++) {
        int o = excl + loc[u];
        offsets[base + u] = o;
        cur[base + u] = o;
    }
    __syncthreads();
    for (int n = t; n < NTOK; n += 1024) {
        int k = idx_i32[n];
        int p = atomicAdd(&cur[k], 1);
        toklist[p] = n;
    }

    float s1 = 0.0f, s2 = 0.0f;
    for (int k = t; k < NUM_EMB; k += 1024) {
        float c = counts[k];
        s1 += cs[k] * DECAY + OMD * c;
        float pb = c / (float)NTOK;
        s2 += pb * logf(pb + 1e-10f);
    }
    float s3 = (t < 256) ? loss_parts[t] : 0.0f;
    #pragma unroll
    for (int m = 32; m >= 1; m >>= 1) {
        s1 += __shfl_xor(s1, m);
        s2 += __shfl_xor(s2, m);
        s3 += __shfl_xor(s3, m);
    }
    __shared__ float w1[16], w2[16], w3[16];
    int lane = t & 63, wid = t >> 6;
    if (lane == 0) { w1[wid] = s1; w2[wid] = s2; w3[wid] = s3; }
    __syncthreads();
    if (t == 0) {
        float n = 0.0f, e2 = 0.0f, ls = 0.0f;
        #pragma unroll
        for (int u = 0; u < 16; u++) { n += w1[u]; e2 += w2[u]; ls += w3[u]; }
        n_out[0] = n;
        out[4194305] = expf(-e2);                 // perplexity
        out[0] = COMMIT * ls / (float)QELEMS;     // loss
    }
}

// ---------------- k_dw_final: 2-wave per-code dw row-sum + EMA outputs --------------
__global__ __launch_bounds__(128)
void k_dw_final(const float* __restrict__ xT, const float* __restrict__ counts,
                const int* __restrict__ offsets, const int* __restrict__ toklist,
                const float* __restrict__ cs, const float* __restrict__ emaw,
                const float* __restrict__ n_in,
                float* __restrict__ out_emb, float* __restrict__ out_cs,
                float* __restrict__ out_emaw) {
    __shared__ float4 sbuf[2][64];
    int k = blockIdx.x;
    int lane = threadIdx.x & 63, wid = threadIdx.x >> 6;
    int c = (int)counts[k];
    int off = offsets[k];
    float a0 = 0, a1 = 0, a2 = 0, a3 = 0;
    for (int t = wid; t < c; t += 2) {
        int tok = toklist[off + t];
        float4 v = *(const float4*)(xT + (size_t)tok * 256 + lane * 4);
        a0 += v.x; a1 += v.y; a2 += v.z; a3 += v.w;
    }
    sbuf[wid][lane] = make_float4(a0, a1, a2, a3);
    __syncthreads();
    if (wid == 0) {
        float4 p0 = sbuf[0][lane], p1 = sbuf[1][lane];
        a0 = p0.x + p1.x; a1 = p0.y + p1.y; a2 = p0.z + p1.z; a3 = p0.w + p1.w;
        float n = n_in[0];
        float pre  = cs[k] * DECAY + OMD * counts[k];
        float cssm = (pre + EPS_) / (n + (float)NUM_EMB * EPS_) * n;
        size_t o = (size_t)k * EMB_DIM + lane * 4;
        float4 ew = *(const float4*)(emaw + o);
        float4 wv;
        wv.x = ew.x * DECAY + OMD * a0;
        wv.y = ew.y * DECAY + OMD * a1;
        wv.z = ew.z * DECAY + OMD * a2;
        wv.w = ew.w * DECAY + OMD * a3;
        *(float4*)(out_emaw + o) = wv;
        float4 obv; obv.x = wv.x / cssm; obv.y = wv.y / cssm;
        obv.z = wv.z / cssm; obv.w = wv.w / cssm;
        *(float4*)(out_emb + o) = obv;
        if (lane == 0) out_cs[k] = cssm;
    }
}

extern "C" void kernel_launch(void* const* d_in, const int* in_sizes, int n_in,
                              void* d_out, int out_size, void* d_ws, size_t ws_size,
                              hipStream_t stream) {
    const float* x    = (const float*)d_in[0];   // [16,256,32,32]
    const float* emb  = (const float*)d_in[1];   // [8192,256]
    const float* cs   = (const float*)d_in[2];   // [8192]
    const float* emaw = (const float*)d_in[3];   // [8192,256]
    float* out = (float*)d_out;

    // workspace layout (bytes)
    char* W = (char*)d_ws;
    _Float16* Ap      = (_Float16*)(W);             //  8,388,608
    _Float16* Bp      = (_Float16*)(W + 8388608);   //  4,194,304
    float*  xT        = (float*) (W + 12582912);    // 16,777,216
    float4* pairs     = (float4*)(W + 29360128);    //  4,194,304
    float* esq        = (float*) (W + 33554432);    //     32,768
    float* counts     = (float*) (W + 33587200);    //     32,768
    float* loss_parts = (float*) (W + 33619968);    //      1,024
    float* n_scal     = (float*) (W + 33621248);    //          4
    int*   offsets    = (int*)   (W + 33621252);    //     32,768
    int*   toklist    = (int*)   (W + 33654020);    //     65,536
    int*   idx_i32    = (int*)   (W + 33719556);    //     65,536

    k_prep     <<<5152, 256, 0, stream>>>(x, emb, Ap, Bp, xT, esq, counts);
    k_dist     <<<4096, 256, 0, stream>>>(Ap, Bp, esq, pairs);
    k_rq       <<<256, 512, 0, stream>>>(pairs, xT, emb, esq, x, idx_i32,
                                         out + 8396802, counts, out + 1, loss_parts);
    k_ivt_stats<<<1, 1024, 0, stream>>>(counts, idx_i32, cs, loss_parts,
                                        offsets, toklist, n_scal, out);
    k_dw_final <<<NUM_EMB, 128, 0, stream>>>(xT, counts, offsets, toklist, cs, emaw,
                                             n_scal, out + 4194306, out + 6291458,
                                             out + 6299650);
}